// Round 12
// baseline (1687.559 us; speedup 1.0000x reference)
//
#include <hip/hip_runtime.h>
#include <hip/hip_bf16.h>
#include <math.h>

#define NEG_SLOPE 0.2f
#define BN_EPS 1e-5f

using short8_t = __attribute__((ext_vector_type(8))) short;
using f32x4    = __attribute__((ext_vector_type(4))) float;

__device__ __forceinline__ unsigned short f2bf(float f) {
    unsigned int u = __float_as_uint(f);
    u += 0x7FFF + ((u >> 16) & 1);          // round-to-nearest-even
    return (unsigned short)(u >> 16);
}
__device__ __forceinline__ float bf2f(unsigned short h) {
    return __uint_as_float(((unsigned int)h) << 16);
}

__global__ void fill_f32(float* p, float v, long long n) {
    long long i = (long long)blockIdx.x * blockDim.x + threadIdx.x;
    long long st = (long long)gridDim.x * blockDim.x;
    for (; i < n; i += st) p[i] = v;
}

__global__ void fill_i32(int* p, int v, long long n) {
    long long i = (long long)blockIdx.x * blockDim.x + threadIdx.x;
    long long st = (long long)gridDim.x * blockDim.x;
    for (; i < n; i += st) p[i] = v;
}

// ---------- CSR build (graph static across layers; built once per call) ----------

__global__ void dst_count(const int* __restrict__ ei, int E, int N,
                          int* __restrict__ count, int* __restrict__ ord)
{
    long long total = (long long)E + N;
    long long st = (long long)gridDim.x * blockDim.x;
    for (long long e = (long long)blockIdx.x * blockDim.x + threadIdx.x; e < total; e += st) {
        int dt = (e < E) ? ei[E + e] : (int)(e - E);
        ord[e] = atomicAdd(&count[dt], 1);
    }
}

__global__ void block_sum(const int* __restrict__ count, int* __restrict__ bsum, int N)
{
    __shared__ int sh[256];
    int b = blockIdx.x, t = threadIdx.x;
    int base = b * 1024;
    int s = 0;
    for (int i = t; i < 1024; i += 256) {
        int j = base + i;
        if (j < N) s += count[j];
    }
    sh[t] = s;
    __syncthreads();
    for (int off = 128; off > 0; off >>= 1) {
        if (t < off) sh[t] += sh[t + off];
        __syncthreads();
    }
    if (t == 0) bsum[b] = sh[0];
}

__global__ void scan_bsum(int* __restrict__ bsum, int nb, int* __restrict__ rowptr, int N, int total)
{
    __shared__ int sh[256];
    int t = threadIdx.x;
    sh[t] = (t < nb) ? bsum[t] : 0;
    __syncthreads();
    for (int off = 1; off < 256; off <<= 1) {
        int u = (t >= off) ? sh[t - off] : 0;
        __syncthreads();
        sh[t] += u;
        __syncthreads();
    }
    if (t < nb) bsum[t] = (t == 0) ? 0 : sh[t - 1];
    if (t == 0) rowptr[N] = total;
}

__global__ void scan_final(const int* __restrict__ count, const int* __restrict__ boff,
                           int* __restrict__ rowptr, int N)
{
    __shared__ int sh[256];
    int b = blockIdx.x, t = threadIdx.x;
    int base = b * 1024 + t * 4;
    int c[4];
    int s = 0;
    #pragma unroll
    for (int i = 0; i < 4; ++i) {
        int j = base + i;
        c[i] = (j < N) ? count[j] : 0;
        s += c[i];
    }
    sh[t] = s;
    __syncthreads();
    for (int off = 1; off < 256; off <<= 1) {
        int u = (t >= off) ? sh[t - off] : 0;
        __syncthreads();
        sh[t] += u;
        __syncthreads();
    }
    int run = boff[b] + ((t == 0) ? 0 : sh[t - 1]);
    #pragma unroll
    for (int i = 0; i < 4; ++i) {
        int j = base + i;
        if (j < N) rowptr[j] = run;
        run += c[i];
    }
}

__global__ void csr_scatter(const int* __restrict__ ei, int E, int N,
                            const int* __restrict__ rowptr, const int* __restrict__ ord,
                            int* __restrict__ srcs)
{
    long long total = (long long)E + N;
    long long st = (long long)gridDim.x * blockDim.x;
    for (long long e = (long long)blockIdx.x * blockDim.x + threadIdx.x; e < total; e += st) {
        int s, dt;
        if (e < E) { s = ei[e]; dt = ei[E + e]; }
        else       { s = dt = (int)(e - E); }
        srcs[rowptr[dt] + ord[e]] = s;
    }
}

// ---------- MFMA GEMM ----------

template<int D>
__global__ void prep_wfrag(const float* __restrict__ W, unsigned short* __restrict__ Wf)
{
    constexpr int CS = D / 32;
    int idx = blockIdx.x * 256 + threadIdx.x;
    if (idx >= 128 * D) return;
    int i    = idx & 7;
    int lane = (idx >> 3) & 63;
    int f    = idx >> 9;
    int ks   = f & 3;
    int cs   = (f >> 2) % CS;
    int wc   = (f >> 2) / CS;
    int k = ks * 32 + ((lane >> 4) << 3) + i;
    int d = wc * (D / 2) + cs * 16 + (lane & 15);
    Wf[idx] = f2bf(W[k * D + d]);
}

// MFMA GEMM: 4 waves (2x2), 32 rows x D cols per block, K=128. B fragments in
// registers from L2-resident Wf; x tile staged to LDS as bf16 with fused BN+ELU.
template<int D, bool BN>
__global__ __launch_bounds__(256, 4) void gemm_mfma(
        const float* __restrict__ x, const unsigned short* __restrict__ Wf,
        const float* __restrict__ colstats, const float* __restrict__ g,
        const float* __restrict__ be, unsigned short* __restrict__ hbuf,
        int N, float invN)
{
    constexpr int CS = D / 32;
    __shared__ unsigned short xs[32 * 136];
    __shared__ float affA[128], affB[128];
    int tid = threadIdx.x, lane = tid & 63, w = tid >> 6;
    int wr = w >> 1, wc = w & 1;
    int n0 = blockIdx.x * 32;

    short8_t bfr[CS][4];
    #pragma unroll
    for (int cs = 0; cs < CS; ++cs)
        #pragma unroll
        for (int ks = 0; ks < 4; ++ks)
            bfr[cs][ks] = *(const short8_t*)(Wf + (((wc * CS + cs) * 4 + ks) << 9) + (lane << 3));

    if (BN) {
        if (tid < 128) {
            float cs_ = colstats[tid], cq = colstats[tid + 128];
            float mu = cs_ * invN;
            float var = cq * invN - mu * mu;
            float s = rsqrtf(var + BN_EPS) * g[tid];
            affA[tid] = s;
            affB[tid] = be[tid] - mu * s;
        }
        __syncthreads();
    }

    for (int jj = tid; jj < 32 * 32; jj += 256) {
        int r = jj >> 5, q = jj & 31;
        float4 v = make_float4(0.f, 0.f, 0.f, 0.f);
        if (n0 + r < N) v = *(const float4*)(x + (long long)(n0 + r) * 128 + q * 4);
        if (BN) {
            int c = q * 4;
            v.x = affA[c]     * v.x + affB[c];
            v.y = affA[c + 1] * v.y + affB[c + 1];
            v.z = affA[c + 2] * v.z + affB[c + 2];
            v.w = affA[c + 3] * v.w + affB[c + 3];
            v.x = (v.x > 0.f) ? v.x : expm1f(v.x);
            v.y = (v.y > 0.f) ? v.y : expm1f(v.y);
            v.z = (v.z > 0.f) ? v.z : expm1f(v.z);
            v.w = (v.w > 0.f) ? v.w : expm1f(v.w);
        }
        ushort4 o;
        o.x = f2bf(v.x); o.y = f2bf(v.y); o.z = f2bf(v.z); o.w = f2bf(v.w);
        *(ushort4*)(xs + r * 136 + q * 4) = o;
    }
    __syncthreads();

    f32x4 acc[CS];
    #pragma unroll
    for (int cs = 0; cs < CS; ++cs) acc[cs] = (f32x4){0.f, 0.f, 0.f, 0.f};

    #pragma unroll
    for (int ks = 0; ks < 4; ++ks) {
        short8_t a = *(const short8_t*)(xs + (wr * 16 + (lane & 15)) * 136
                                           + ks * 32 + ((lane >> 4) << 3));
        #pragma unroll
        for (int cs = 0; cs < CS; ++cs)
            acc[cs] = __builtin_amdgcn_mfma_f32_16x16x32_bf16(a, bfr[cs][ks], acc[cs], 0, 0, 0);
    }

    int mrow = wr * 16 + ((lane >> 4) << 2);
    int dcol = wc * (D / 2) + (lane & 15);
    #pragma unroll
    for (int cs = 0; cs < CS; ++cs)
        #pragma unroll
        for (int r = 0; r < 4; ++r) {
            int n = n0 + mrow + r;
            if (n < N) hbuf[(long long)n * D + dcol + cs * 16] = f2bf(acc[cs][r]);
        }
}

// attention projections from bf16 h: one thread per (node, head)
template<int H, int C>
__global__ void calc_al(const unsigned short* __restrict__ hbuf,
                        const float* __restrict__ a_s, const float* __restrict__ a_d,
                        float* __restrict__ als, float* __restrict__ ald, int N)
{
    int idx = blockIdx.x * blockDim.x + threadIdx.x;
    if (idx >= N * H) return;
    int n = idx / H, hh = idx % H;
    const unsigned short* hp = hbuf + (long long)n * H * C + hh * C;
    float s1 = 0.f, s2 = 0.f;
    #pragma unroll
    for (int c = 0; c < C; c += 4) {
        ushort4 hv = *(const ushort4*)(hp + c);
        float f0 = bf2f(hv.x), f1 = bf2f(hv.y), f2 = bf2f(hv.z), f3 = bf2f(hv.w);
        s1 += f0 * a_s[hh * C + c]     + f1 * a_s[hh * C + c + 1]
            + f2 * a_s[hh * C + c + 2] + f3 * a_s[hh * C + c + 3];
        s2 += f0 * a_d[hh * C + c]     + f1 * a_d[hh * C + c + 1]
            + f2 * a_d[hh * C + c + 2] + f3 * a_d[hh * C + c + 3];
    }
    als[idx] = s1;
    ald[idx] = s2;
}

// aggregate v5: v4 + fused BN statistics (R11: standalone bn_stats was a 55µs
// dirty-L2 re-read of 25.6MB; here the values are summed from registers).
// Epilogue: shfl_xor butterfly over node-groups -> LDS -> wave0 atomics.
template<int H, int C>
__global__ __launch_bounds__(256) void gat_aggregate_v5(
        const int* __restrict__ rowptr, const int* __restrict__ srcs,
        const float* __restrict__ als, const float* __restrict__ ald,
        const unsigned short* __restrict__ hbuf, float* __restrict__ agg,
        float* __restrict__ colsum, int N)
{
    constexpr int D = H * C;
    constexpr int TPN = D / 8;        // threads per node (16 or 8)
    constexpr int NPB = 256 / TPN;    // nodes per block
    __shared__ float red[4][TPN * 16];
    int tid = threadIdx.x;
    int g = tid / TPN, l = tid % TPN;
    int n = blockIdx.x * NPB + g;
    bool active = (n < N);
    int c0 = l * 8;
    int hh = c0 / C;
    float aldv = active ? ald[(long long)n * H + hh] : 0.f;
    int beg = 0, end = 0;
    if (active) { beg = rowptr[n]; end = rowptr[n + 1]; }

    float wsum = 0.f;
    float acc[8];
    #pragma unroll
    for (int i = 0; i < 8; ++i) acc[i] = 0.f;

    int e = beg;
    for (; e + 4 <= end; e += 4) {
        int s0 = srcs[e], s1 = srcs[e + 1], s2 = srcs[e + 2], s3 = srcs[e + 3];
        float v0 = als[(long long)s0 * H + hh] + aldv;
        float v1 = als[(long long)s1 * H + hh] + aldv;
        float v2 = als[(long long)s2 * H + hh] + aldv;
        float v3 = als[(long long)s3 * H + hh] + aldv;
        v0 = (v0 >= 0.f) ? v0 : NEG_SLOPE * v0;
        v1 = (v1 >= 0.f) ? v1 : NEG_SLOPE * v1;
        v2 = (v2 >= 0.f) ? v2 : NEG_SLOPE * v2;
        v3 = (v3 >= 0.f) ? v3 : NEG_SLOPE * v3;
        float w0 = __expf(v0), w1 = __expf(v1), w2 = __expf(v2), w3 = __expf(v3);
        float4 q0 = *(const float4*)(hbuf + (long long)s0 * D + c0);
        float4 q1 = *(const float4*)(hbuf + (long long)s1 * D + c0);
        float4 q2 = *(const float4*)(hbuf + (long long)s2 * D + c0);
        float4 q3 = *(const float4*)(hbuf + (long long)s3 * D + c0);
        wsum += w0 + w1 + w2 + w3;
        const float* qf0 = (const float*)&q0;
        const float* qf1 = (const float*)&q1;
        const float* qf2 = (const float*)&q2;
        const float* qf3 = (const float*)&q3;
        #pragma unroll
        for (int i = 0; i < 4; ++i) {
            unsigned int u0 = __float_as_uint(qf0[i]);
            unsigned int u1 = __float_as_uint(qf1[i]);
            unsigned int u2 = __float_as_uint(qf2[i]);
            unsigned int u3 = __float_as_uint(qf3[i]);
            acc[2*i]   += w0 * __uint_as_float(u0 << 16)
                        + w1 * __uint_as_float(u1 << 16)
                        + w2 * __uint_as_float(u2 << 16)
                        + w3 * __uint_as_float(u3 << 16);
            acc[2*i+1] += w0 * __uint_as_float(u0 & 0xFFFF0000u)
                        + w1 * __uint_as_float(u1 & 0xFFFF0000u)
                        + w2 * __uint_as_float(u2 & 0xFFFF0000u)
                        + w3 * __uint_as_float(u3 & 0xFFFF0000u);
        }
    }
    for (; e < end; ++e) {
        int s = srcs[e];
        float v = als[(long long)s * H + hh] + aldv;
        v = (v >= 0.f) ? v : NEG_SLOPE * v;
        float w = __expf(v);
        float4 q = *(const float4*)(hbuf + (long long)s * D + c0);
        const float* qf = (const float*)&q;
        wsum += w;
        #pragma unroll
        for (int i = 0; i < 4; ++i) {
            unsigned int u = __float_as_uint(qf[i]);
            acc[2*i]   += w * __uint_as_float(u << 16);
            acc[2*i+1] += w * __uint_as_float(u & 0xFFFF0000u);
        }
    }
    float inv = active ? 1.f / (wsum + 1e-16f) : 0.f;
    float sv[16];
    #pragma unroll
    for (int i = 0; i < 8; ++i) {
        float o = acc[i] * inv;
        sv[i] = o;
        sv[8 + i] = o * o;
        acc[i] = o;
    }
    if (active) {
        *(float4*)(agg + (long long)n * D + c0)     = make_float4(acc[0], acc[1], acc[2], acc[3]);
        *(float4*)(agg + (long long)n * D + c0 + 4) = make_float4(acc[4], acc[5], acc[6], acc[7]);
    }

    // fused BN stats: butterfly over node-groups within wave
    #pragma unroll
    for (int off = TPN; off < 64; off <<= 1)
        #pragma unroll
        for (int j = 0; j < 16; ++j)
            sv[j] += __shfl_xor(sv[j], off);

    int w4 = tid >> 6, lane = tid & 63;
    if (lane < TPN) {
        #pragma unroll
        for (int j = 0; j < 16; ++j) red[w4][lane * 16 + j] = sv[j];
    }
    __syncthreads();
    if (w4 == 0 && lane < TPN) {
        #pragma unroll
        for (int ww = 1; ww < 4; ++ww)
            #pragma unroll
            for (int j = 0; j < 16; ++j) sv[j] += red[ww][lane * 16 + j];
        int cc = lane * 8;
        #pragma unroll
        for (int j = 0; j < 8; ++j) {
            atomicAdd(&colsum[cc + j], sv[j]);
            atomicAdd(&colsum[128 + cc + j], sv[8 + j]);
        }
    }
}

// bn_apply_v2 (final output only): 256-thread blocks, float4 in/out.
template<int D>
__global__ __launch_bounds__(256) void bn_apply_v2(
        const float* __restrict__ agg, const float* __restrict__ colsum,
        const float* __restrict__ g, const float* __restrict__ be,
        float* __restrict__ out, int N, float invN)
{
    constexpr int TPR = D / 4;
    constexpr int RPB = 256 / TPR;
    __shared__ float affA[D], affB[D];
    int tid = threadIdx.x;
    if (tid < D) {
        float mu = colsum[tid] * invN;
        float var = colsum[128 + tid] * invN - mu * mu;
        float s = rsqrtf(var + BN_EPS) * g[tid];
        affA[tid] = s;
        affB[tid] = be[tid] - mu * s;
    }
    __syncthreads();
    int rg = tid / TPR, cl = tid % TPR;
    int c = cl * 4;
    float a0 = affA[c], a1 = affA[c+1], a2 = affA[c+2], a3 = affA[c+3];
    float b0 = affB[c], b1 = affB[c+1], b2 = affB[c+2], b3 = affB[c+3];
    for (int r = blockIdx.x * RPB + rg; r < N; r += gridDim.x * RPB) {
        float4 v = *(const float4*)(agg + (long long)r * D + c);
        v.x = a0 * v.x + b0; v.y = a1 * v.y + b1;
        v.z = a2 * v.z + b2; v.w = a3 * v.w + b3;
        v.x = (v.x > 0.f) ? v.x : expm1f(v.x);
        v.y = (v.y > 0.f) ? v.y : expm1f(v.y);
        v.z = (v.z > 0.f) ? v.z : expm1f(v.z);
        v.w = (v.w > 0.f) ? v.w : expm1f(v.w);
        *(float4*)(out + (long long)r * D + c) = v;
    }
}

template<int H, int C, bool BN>
static void run_layer(const float* xin, int N,
                      const int* rowptr, const int* srcs,
                      const unsigned short* Wf, const float* a_s, const float* a_d,
                      const float* prev_stats, const float* prev_g, const float* prev_be,
                      unsigned short* hbuf, float* als, float* ald,
                      float* stats_out, float* agg,
                      hipStream_t stream)
{
    constexpr int D = H * C;
    constexpr int NPB = 256 / (D / 8);
    float invN = 1.f / (float)N;
    gemm_mfma<D, BN><<<(N + 31) / 32, 256, 0, stream>>>(
        xin, Wf, prev_stats, prev_g, prev_be, hbuf, N, invN);
    calc_al<H, C><<<(N * H + 255) / 256, 256, 0, stream>>>(hbuf, a_s, a_d, als, ald, N);
    gat_aggregate_v5<H, C><<<(N + NPB - 1) / NPB, 256, 0, stream>>>(
        rowptr, srcs, als, ald, hbuf, agg, stats_out, N);
}

extern "C" void kernel_launch(void* const* d_in, const int* in_sizes, int n_in,
                              void* d_out, int out_size, void* d_ws, size_t ws_size,
                              hipStream_t stream)
{
    const float* x   = (const float*)d_in[0];
    const int*   ei  = (const int*)d_in[1];
    const float* W1  = (const float*)d_in[2];
    const float* as1 = (const float*)d_in[3];
    const float* ad1 = (const float*)d_in[4];
    const float* g1  = (const float*)d_in[6];
    const float* be1 = (const float*)d_in[7];
    const float* W2  = (const float*)d_in[8];
    const float* as2 = (const float*)d_in[9];
    const float* ad2 = (const float*)d_in[10];
    const float* g2  = (const float*)d_in[12];
    const float* be2 = (const float*)d_in[13];
    const float* W3  = (const float*)d_in[14];
    const float* as3 = (const float*)d_in[15];
    const float* ad3 = (const float*)d_in[16];
    const float* g3  = (const float*)d_in[18];
    const float* be3 = (const float*)d_in[19];

    const int N = in_sizes[0] / 128;
    const int E = in_sizes[1] / 2;
    const int NB = (N + 1023) / 1024;

    float* ws   = (float*)d_ws;
    float* aggA = ws;                            // N*128
    float* aggB = aggA + (long long)N * 128;     // N*128
    float* als  = aggB + (long long)N * 128;     // N*4
    float* ald  = als  + (long long)N * 4;       // N*4
    float* cs0  = ald  + (long long)N * 4;       // 256
    float* cs1  = cs0 + 256;                     // 256
    float* cs2  = cs1 + 256;                     // 256
    unsigned short* hbuf = (unsigned short*)(cs2 + 256);        // N*128 bf16
    int*   rowptr = (int*)(hbuf + (long long)N * 128);          // N+1
    int*   count  = rowptr + (N + 1);            // N
    int*   bsum   = count + N;                   // <=256
    int*   ord    = bsum + 256;                  // E+N
    int*   srcs   = ord + ((long long)E + N);    // E+N
    unsigned short* wf1 = (unsigned short*)(srcs + ((long long)E + N)); // 128*128
    unsigned short* wf2 = wf1 + 128 * 128;                              // 128*128
    unsigned short* wf3 = wf2 + 128 * 128;                              // 128*64

    // ---- one-time prep: W -> fragment-ordered bf16 ----
    prep_wfrag<128><<<64, 256, 0, stream>>>(W1, wf1);
    prep_wfrag<128><<<64, 256, 0, stream>>>(W2, wf2);
    prep_wfrag<64><<<32, 256, 0, stream>>>(W3, wf3);

    // ---- CSR build (once; reused by all 3 layers) ----
    fill_i32<<<128, 256, 0, stream>>>(count, 0, N);
    fill_f32<<<1, 768, 0, stream>>>(cs0, 0.f, 768);
    dst_count<<<2048, 256, 0, stream>>>(ei, E, N, count, ord);
    block_sum<<<NB, 256, 0, stream>>>(count, bsum, N);
    scan_bsum<<<1, 256, 0, stream>>>(bsum, NB, rowptr, N, E + N);
    scan_final<<<NB, 256, 0, stream>>>(count, bsum, rowptr, N);
    csr_scatter<<<2048, 256, 0, stream>>>(ei, E, N, rowptr, ord, srcs);

    // L1: x -> aggA (no input BN); stats -> cs0
    run_layer<4, 32, false>(x, N, rowptr, srcs, wf1, as1, ad1,
                            nullptr, nullptr, nullptr,
                            hbuf, als, ald, cs0, aggA, stream);
    // L2: aggA (+BN1+ELU fused) -> aggB; stats -> cs1
    run_layer<4, 32, true>(aggA, N, rowptr, srcs, wf2, as2, ad2,
                           cs0, g1, be1,
                           hbuf, als, ald, cs1, aggB, stream);
    // L3: aggB (+BN2+ELU fused) -> aggA (D=64); stats -> cs2
    run_layer<1, 64, true>(aggB, N, rowptr, srcs, wf3, as3, ad3,
                           cs1, g2, be2,
                           hbuf, als, ald, cs2, aggA, stream);
    // final BN3 + ELU -> out
    bn_apply_v2<64><<<2048, 256, 0, stream>>>(aggA, cs2, g3, be3, (float*)d_out, N, 1.f / (float)N);
}

// Round 13
// 247.572 us; speedup vs baseline: 6.8164x; 6.8164x over previous
//
#include <hip/hip_runtime.h>
#include <hip/hip_bf16.h>
#include <math.h>

#define NEG_SLOPE 0.2f
#define BN_EPS 1e-5f

using short8_t = __attribute__((ext_vector_type(8))) short;
using f32x4    = __attribute__((ext_vector_type(4))) float;

__device__ __forceinline__ unsigned short f2bf(float f) {
    unsigned int u = __float_as_uint(f);
    u += 0x7FFF + ((u >> 16) & 1);          // round-to-nearest-even
    return (unsigned short)(u >> 16);
}
__device__ __forceinline__ float bf2f(unsigned short h) {
    return __uint_as_float(((unsigned int)h) << 16);
}

__global__ void fill_i32(int* p, int v, long long n) {
    long long i = (long long)blockIdx.x * blockDim.x + threadIdx.x;
    long long st = (long long)gridDim.x * blockDim.x;
    for (; i < n; i += st) p[i] = v;
}

// ---------- CSR build (graph static across layers; built once per call) ----------

__global__ void dst_count(const int* __restrict__ ei, int E, int N,
                          int* __restrict__ count, int* __restrict__ ord)
{
    long long total = (long long)E + N;
    long long st = (long long)gridDim.x * blockDim.x;
    for (long long e = (long long)blockIdx.x * blockDim.x + threadIdx.x; e < total; e += st) {
        int dt = (e < E) ? ei[E + e] : (int)(e - E);
        ord[e] = atomicAdd(&count[dt], 1);
    }
}

__global__ void block_sum(const int* __restrict__ count, int* __restrict__ bsum, int N)
{
    __shared__ int sh[256];
    int b = blockIdx.x, t = threadIdx.x;
    int base = b * 1024;
    int s = 0;
    for (int i = t; i < 1024; i += 256) {
        int j = base + i;
        if (j < N) s += count[j];
    }
    sh[t] = s;
    __syncthreads();
    for (int off = 128; off > 0; off >>= 1) {
        if (t < off) sh[t] += sh[t + off];
        __syncthreads();
    }
    if (t == 0) bsum[b] = sh[0];
}

__global__ void scan_bsum(int* __restrict__ bsum, int nb, int* __restrict__ rowptr, int N, int total)
{
    __shared__ int sh[256];
    int t = threadIdx.x;
    sh[t] = (t < nb) ? bsum[t] : 0;
    __syncthreads();
    for (int off = 1; off < 256; off <<= 1) {
        int u = (t >= off) ? sh[t - off] : 0;
        __syncthreads();
        sh[t] += u;
        __syncthreads();
    }
    if (t < nb) bsum[t] = (t == 0) ? 0 : sh[t - 1];
    if (t == 0) rowptr[N] = total;
}

__global__ void scan_final(const int* __restrict__ count, const int* __restrict__ boff,
                           int* __restrict__ rowptr, int N)
{
    __shared__ int sh[256];
    int b = blockIdx.x, t = threadIdx.x;
    int base = b * 1024 + t * 4;
    int c[4];
    int s = 0;
    #pragma unroll
    for (int i = 0; i < 4; ++i) {
        int j = base + i;
        c[i] = (j < N) ? count[j] : 0;
        s += c[i];
    }
    sh[t] = s;
    __syncthreads();
    for (int off = 1; off < 256; off <<= 1) {
        int u = (t >= off) ? sh[t - off] : 0;
        __syncthreads();
        sh[t] += u;
        __syncthreads();
    }
    int run = boff[b] + ((t == 0) ? 0 : sh[t - 1]);
    #pragma unroll
    for (int i = 0; i < 4; ++i) {
        int j = base + i;
        if (j < N) rowptr[j] = run;
        run += c[i];
    }
}

__global__ void csr_scatter(const int* __restrict__ ei, int E, int N,
                            const int* __restrict__ rowptr, const int* __restrict__ ord,
                            int* __restrict__ srcs)
{
    long long total = (long long)E + N;
    long long st = (long long)gridDim.x * blockDim.x;
    for (long long e = (long long)blockIdx.x * blockDim.x + threadIdx.x; e < total; e += st) {
        int s, dt;
        if (e < E) { s = ei[e]; dt = ei[E + e]; }
        else       { s = dt = (int)(e - E); }
        srcs[rowptr[dt] + ord[e]] = s;
    }
}

// ---------- MFMA GEMM ----------

template<int D>
__global__ void prep_wfrag(const float* __restrict__ W, unsigned short* __restrict__ Wf)
{
    constexpr int CS = D / 32;
    int idx = blockIdx.x * 256 + threadIdx.x;
    if (idx >= 128 * D) return;
    int i    = idx & 7;
    int lane = (idx >> 3) & 63;
    int f    = idx >> 9;
    int ks   = f & 3;
    int cs   = (f >> 2) % CS;
    int wc   = (f >> 2) / CS;
    int k = ks * 32 + ((lane >> 4) << 3) + i;
    int d = wc * (D / 2) + cs * 16 + (lane & 15);
    Wf[idx] = f2bf(W[k * D + d]);
}

// MFMA GEMM: 4 waves (2x2), 32 rows x D cols per block, K=128. B fragments in
// registers from L2-resident Wf; x tile staged to LDS as bf16 with fused BN+ELU.
template<int D, bool BN>
__global__ __launch_bounds__(256, 4) void gemm_mfma(
        const float* __restrict__ x, const unsigned short* __restrict__ Wf,
        const float* __restrict__ colstats, const float* __restrict__ g,
        const float* __restrict__ be, unsigned short* __restrict__ hbuf,
        int N, float invN)
{
    constexpr int CS = D / 32;
    __shared__ unsigned short xs[32 * 136];
    __shared__ float affA[128], affB[128];
    int tid = threadIdx.x, lane = tid & 63, w = tid >> 6;
    int wr = w >> 1, wc = w & 1;
    int n0 = blockIdx.x * 32;

    short8_t bfr[CS][4];
    #pragma unroll
    for (int cs = 0; cs < CS; ++cs)
        #pragma unroll
        for (int ks = 0; ks < 4; ++ks)
            bfr[cs][ks] = *(const short8_t*)(Wf + (((wc * CS + cs) * 4 + ks) << 9) + (lane << 3));

    if (BN) {
        if (tid < 128) {
            float cs_ = colstats[tid], cq = colstats[tid + 128];
            float mu = cs_ * invN;
            float var = cq * invN - mu * mu;
            float s = rsqrtf(var + BN_EPS) * g[tid];
            affA[tid] = s;
            affB[tid] = be[tid] - mu * s;
        }
        __syncthreads();
    }

    for (int jj = tid; jj < 32 * 32; jj += 256) {
        int r = jj >> 5, q = jj & 31;
        float4 v = make_float4(0.f, 0.f, 0.f, 0.f);
        if (n0 + r < N) v = *(const float4*)(x + (long long)(n0 + r) * 128 + q * 4);
        if (BN) {
            int c = q * 4;
            v.x = affA[c]     * v.x + affB[c];
            v.y = affA[c + 1] * v.y + affB[c + 1];
            v.z = affA[c + 2] * v.z + affB[c + 2];
            v.w = affA[c + 3] * v.w + affB[c + 3];
            v.x = (v.x > 0.f) ? v.x : expm1f(v.x);
            v.y = (v.y > 0.f) ? v.y : expm1f(v.y);
            v.z = (v.z > 0.f) ? v.z : expm1f(v.z);
            v.w = (v.w > 0.f) ? v.w : expm1f(v.w);
        }
        ushort4 o;
        o.x = f2bf(v.x); o.y = f2bf(v.y); o.z = f2bf(v.z); o.w = f2bf(v.w);
        *(ushort4*)(xs + r * 136 + q * 4) = o;
    }
    __syncthreads();

    f32x4 acc[CS];
    #pragma unroll
    for (int cs = 0; cs < CS; ++cs) acc[cs] = (f32x4){0.f, 0.f, 0.f, 0.f};

    #pragma unroll
    for (int ks = 0; ks < 4; ++ks) {
        short8_t a = *(const short8_t*)(xs + (wr * 16 + (lane & 15)) * 136
                                           + ks * 32 + ((lane >> 4) << 3));
        #pragma unroll
        for (int cs = 0; cs < CS; ++cs)
            acc[cs] = __builtin_amdgcn_mfma_f32_16x16x32_bf16(a, bfr[cs][ks], acc[cs], 0, 0, 0);
    }

    int mrow = wr * 16 + ((lane >> 4) << 2);
    int dcol = wc * (D / 2) + (lane & 15);
    #pragma unroll
    for (int cs = 0; cs < CS; ++cs)
        #pragma unroll
        for (int r = 0; r < 4; ++r) {
            int n = n0 + mrow + r;
            if (n < N) hbuf[(long long)n * D + dcol + cs * 16] = f2bf(acc[cs][r]);
        }
}

// attention projections from bf16 h: one thread per (node, head)
template<int H, int C>
__global__ void calc_al(const unsigned short* __restrict__ hbuf,
                        const float* __restrict__ a_s, const float* __restrict__ a_d,
                        float* __restrict__ als, float* __restrict__ ald, int N)
{
    int idx = blockIdx.x * blockDim.x + threadIdx.x;
    if (idx >= N * H) return;
    int n = idx / H, hh = idx % H;
    const unsigned short* hp = hbuf + (long long)n * H * C + hh * C;
    float s1 = 0.f, s2 = 0.f;
    #pragma unroll
    for (int c = 0; c < C; c += 4) {
        ushort4 hv = *(const ushort4*)(hp + c);
        float f0 = bf2f(hv.x), f1 = bf2f(hv.y), f2 = bf2f(hv.z), f3 = bf2f(hv.w);
        s1 += f0 * a_s[hh * C + c]     + f1 * a_s[hh * C + c + 1]
            + f2 * a_s[hh * C + c + 2] + f3 * a_s[hh * C + c + 3];
        s2 += f0 * a_d[hh * C + c]     + f1 * a_d[hh * C + c + 1]
            + f2 * a_d[hh * C + c + 2] + f3 * a_d[hh * C + c + 3];
    }
    als[idx] = s1;
    ald[idx] = s2;
}

// aggregate v5b: fused BN stats WITHOUT contended atomics (R12: 3125-contender
// atomicAdd on 256 addresses serialized at ~200ns each = 617µs). Wave/LDS
// reduce as before, then wave0 stores per-block partials (coalesced, no
// contention); reduce_stats sums them.
template<int H, int C>
__global__ __launch_bounds__(256) void gat_aggregate_v5(
        const int* __restrict__ rowptr, const int* __restrict__ srcs,
        const float* __restrict__ als, const float* __restrict__ ald,
        const unsigned short* __restrict__ hbuf, float* __restrict__ agg,
        float* __restrict__ part, int N)
{
    constexpr int D = H * C;
    constexpr int TPN = D / 8;        // threads per node (16 or 8)
    constexpr int NPB = 256 / TPN;    // nodes per block
    __shared__ float red[4][TPN * 16];
    int tid = threadIdx.x;
    int g = tid / TPN, l = tid % TPN;
    int n = blockIdx.x * NPB + g;
    bool active = (n < N);
    int c0 = l * 8;
    int hh = c0 / C;
    float aldv = active ? ald[(long long)n * H + hh] : 0.f;
    int beg = 0, end = 0;
    if (active) { beg = rowptr[n]; end = rowptr[n + 1]; }

    float wsum = 0.f;
    float acc[8];
    #pragma unroll
    for (int i = 0; i < 8; ++i) acc[i] = 0.f;

    int e = beg;
    for (; e + 4 <= end; e += 4) {
        int s0 = srcs[e], s1 = srcs[e + 1], s2 = srcs[e + 2], s3 = srcs[e + 3];
        float v0 = als[(long long)s0 * H + hh] + aldv;
        float v1 = als[(long long)s1 * H + hh] + aldv;
        float v2 = als[(long long)s2 * H + hh] + aldv;
        float v3 = als[(long long)s3 * H + hh] + aldv;
        v0 = (v0 >= 0.f) ? v0 : NEG_SLOPE * v0;
        v1 = (v1 >= 0.f) ? v1 : NEG_SLOPE * v1;
        v2 = (v2 >= 0.f) ? v2 : NEG_SLOPE * v2;
        v3 = (v3 >= 0.f) ? v3 : NEG_SLOPE * v3;
        float w0 = __expf(v0), w1 = __expf(v1), w2 = __expf(v2), w3 = __expf(v3);
        float4 q0 = *(const float4*)(hbuf + (long long)s0 * D + c0);
        float4 q1 = *(const float4*)(hbuf + (long long)s1 * D + c0);
        float4 q2 = *(const float4*)(hbuf + (long long)s2 * D + c0);
        float4 q3 = *(const float4*)(hbuf + (long long)s3 * D + c0);
        wsum += w0 + w1 + w2 + w3;
        const float* qf0 = (const float*)&q0;
        const float* qf1 = (const float*)&q1;
        const float* qf2 = (const float*)&q2;
        const float* qf3 = (const float*)&q3;
        #pragma unroll
        for (int i = 0; i < 4; ++i) {
            unsigned int u0 = __float_as_uint(qf0[i]);
            unsigned int u1 = __float_as_uint(qf1[i]);
            unsigned int u2 = __float_as_uint(qf2[i]);
            unsigned int u3 = __float_as_uint(qf3[i]);
            acc[2*i]   += w0 * __uint_as_float(u0 << 16)
                        + w1 * __uint_as_float(u1 << 16)
                        + w2 * __uint_as_float(u2 << 16)
                        + w3 * __uint_as_float(u3 << 16);
            acc[2*i+1] += w0 * __uint_as_float(u0 & 0xFFFF0000u)
                        + w1 * __uint_as_float(u1 & 0xFFFF0000u)
                        + w2 * __uint_as_float(u2 & 0xFFFF0000u)
                        + w3 * __uint_as_float(u3 & 0xFFFF0000u);
        }
    }
    for (; e < end; ++e) {
        int s = srcs[e];
        float v = als[(long long)s * H + hh] + aldv;
        v = (v >= 0.f) ? v : NEG_SLOPE * v;
        float w = __expf(v);
        float4 q = *(const float4*)(hbuf + (long long)s * D + c0);
        const float* qf = (const float*)&q;
        wsum += w;
        #pragma unroll
        for (int i = 0; i < 4; ++i) {
            unsigned int u = __float_as_uint(qf[i]);
            acc[2*i]   += w * __uint_as_float(u << 16);
            acc[2*i+1] += w * __uint_as_float(u & 0xFFFF0000u);
        }
    }
    float inv = active ? 1.f / (wsum + 1e-16f) : 0.f;
    float sv[16];
    #pragma unroll
    for (int i = 0; i < 8; ++i) {
        float o = acc[i] * inv;
        sv[i] = o;
        sv[8 + i] = o * o;
        acc[i] = o;
    }
    if (active) {
        *(float4*)(agg + (long long)n * D + c0)     = make_float4(acc[0], acc[1], acc[2], acc[3]);
        *(float4*)(agg + (long long)n * D + c0 + 4) = make_float4(acc[4], acc[5], acc[6], acc[7]);
    }

    // butterfly over node-groups within wave
    #pragma unroll
    for (int off = TPN; off < 64; off <<= 1)
        #pragma unroll
        for (int j = 0; j < 16; ++j)
            sv[j] += __shfl_xor(sv[j], off);

    int w4 = tid >> 6, lane = tid & 63;
    if (lane < TPN) {
        #pragma unroll
        for (int j = 0; j < 16; ++j) red[w4][lane * 16 + j] = sv[j];
    }
    __syncthreads();
    if (w4 == 0 && lane < TPN) {
        #pragma unroll
        for (int ww = 1; ww < 4; ++ww)
            #pragma unroll
            for (int j = 0; j < 16; ++j) sv[j] += red[ww][lane * 16 + j];
        // per-block partial store: block chunk = 2*D floats, lane writes 16
        float* p = part + (long long)blockIdx.x * (2 * D) + lane * 16;
        *(float4*)(p)      = make_float4(sv[0],  sv[1],  sv[2],  sv[3]);
        *(float4*)(p + 4)  = make_float4(sv[4],  sv[5],  sv[6],  sv[7]);
        *(float4*)(p + 8)  = make_float4(sv[8],  sv[9],  sv[10], sv[11]);
        *(float4*)(p + 12) = make_float4(sv[12], sv[13], sv[14], sv[15]);
    }
}

// reduce per-block partials -> colsum (no atomics; 1 block per output scalar).
// part chunk layout per block: lane l, j<8 -> sum of col l*8+j; j>=8 -> sumsq.
template<int D>
__global__ __launch_bounds__(256) void reduce_stats(
        const float* __restrict__ part, int nblk, float* __restrict__ colsum)
{
    __shared__ float sh[256];
    int f = blockIdx.x;              // 0..2D-1
    int t = threadIdx.x;
    int col = (f < D) ? f : (f - D);
    int off = (col / 8) * 16 + (col % 8) + ((f < D) ? 0 : 8);
    float s = 0.f;
    for (int i = t; i < nblk; i += 256)
        s += part[(long long)i * (2 * D) + off];
    sh[t] = s;
    __syncthreads();
    for (int o = 128; o > 0; o >>= 1) {
        if (t < o) sh[t] += sh[t + o];
        __syncthreads();
    }
    if (t == 0) colsum[(f < D) ? f : (128 + f - D)] = sh[0];
}

// bn_apply_v2 (final output only): 256-thread blocks, float4 in/out.
template<int D>
__global__ __launch_bounds__(256) void bn_apply_v2(
        const float* __restrict__ agg, const float* __restrict__ colsum,
        const float* __restrict__ g, const float* __restrict__ be,
        float* __restrict__ out, int N, float invN)
{
    constexpr int TPR = D / 4;
    constexpr int RPB = 256 / TPR;
    __shared__ float affA[D], affB[D];
    int tid = threadIdx.x;
    if (tid < D) {
        float mu = colsum[tid] * invN;
        float var = colsum[128 + tid] * invN - mu * mu;
        float s = rsqrtf(var + BN_EPS) * g[tid];
        affA[tid] = s;
        affB[tid] = be[tid] - mu * s;
    }
    __syncthreads();
    int rg = tid / TPR, cl = tid % TPR;
    int c = cl * 4;
    float a0 = affA[c], a1 = affA[c+1], a2 = affA[c+2], a3 = affA[c+3];
    float b0 = affB[c], b1 = affB[c+1], b2 = affB[c+2], b3 = affB[c+3];
    for (int r = blockIdx.x * RPB + rg; r < N; r += gridDim.x * RPB) {
        float4 v = *(const float4*)(agg + (long long)r * D + c);
        v.x = a0 * v.x + b0; v.y = a1 * v.y + b1;
        v.z = a2 * v.z + b2; v.w = a3 * v.w + b3;
        v.x = (v.x > 0.f) ? v.x : expm1f(v.x);
        v.y = (v.y > 0.f) ? v.y : expm1f(v.y);
        v.z = (v.z > 0.f) ? v.z : expm1f(v.z);
        v.w = (v.w > 0.f) ? v.w : expm1f(v.w);
        *(float4*)(out + (long long)r * D + c) = v;
    }
}

template<int H, int C, bool BN>
static void run_layer(const float* xin, int N,
                      const int* rowptr, const int* srcs,
                      const unsigned short* Wf, const float* a_s, const float* a_d,
                      const float* prev_stats, const float* prev_g, const float* prev_be,
                      unsigned short* hbuf, float* als, float* ald,
                      float* part, float* stats_out, float* agg,
                      hipStream_t stream)
{
    constexpr int D = H * C;
    constexpr int NPB = 256 / (D / 8);
    int nblk = (N + NPB - 1) / NPB;
    float invN = 1.f / (float)N;
    gemm_mfma<D, BN><<<(N + 31) / 32, 256, 0, stream>>>(
        xin, Wf, prev_stats, prev_g, prev_be, hbuf, N, invN);
    calc_al<H, C><<<(N * H + 255) / 256, 256, 0, stream>>>(hbuf, a_s, a_d, als, ald, N);
    gat_aggregate_v5<H, C><<<nblk, 256, 0, stream>>>(
        rowptr, srcs, als, ald, hbuf, agg, part, N);
    reduce_stats<D><<<2 * D, 256, 0, stream>>>(part, nblk, stats_out);
}

extern "C" void kernel_launch(void* const* d_in, const int* in_sizes, int n_in,
                              void* d_out, int out_size, void* d_ws, size_t ws_size,
                              hipStream_t stream)
{
    const float* x   = (const float*)d_in[0];
    const int*   ei  = (const int*)d_in[1];
    const float* W1  = (const float*)d_in[2];
    const float* as1 = (const float*)d_in[3];
    const float* ad1 = (const float*)d_in[4];
    const float* g1  = (const float*)d_in[6];
    const float* be1 = (const float*)d_in[7];
    const float* W2  = (const float*)d_in[8];
    const float* as2 = (const float*)d_in[9];
    const float* ad2 = (const float*)d_in[10];
    const float* g2  = (const float*)d_in[12];
    const float* be2 = (const float*)d_in[13];
    const float* W3  = (const float*)d_in[14];
    const float* as3 = (const float*)d_in[15];
    const float* ad3 = (const float*)d_in[16];
    const float* g3  = (const float*)d_in[18];
    const float* be3 = (const float*)d_in[19];

    const int N = in_sizes[0] / 128;
    const int E = in_sizes[1] / 2;
    const int NB = (N + 1023) / 1024;
    const int NBLK128 = (N + 15) / 16;          // aggregate blocks at D=128

    float* ws   = (float*)d_ws;
    float* aggA = ws;                            // N*128
    float* aggB = aggA + (long long)N * 128;     // N*128
    float* als  = aggB + (long long)N * 128;     // N*4
    float* ald  = als  + (long long)N * 4;       // N*4
    float* cs0  = ald  + (long long)N * 4;       // 256
    float* cs1  = cs0 + 256;                     // 256
    float* cs2  = cs1 + 256;                     // 256
    unsigned short* hbuf = (unsigned short*)(cs2 + 256);        // N*128 bf16
    int*   rowptr = (int*)(hbuf + (long long)N * 128);          // N+1
    int*   count  = rowptr + (N + 1);            // N
    int*   bsum   = count + N;                   // <=256
    int*   ord    = bsum + 256;                  // E+N
    int*   srcs   = ord + ((long long)E + N);    // E+N
    unsigned short* wf1 = (unsigned short*)(srcs + ((long long)E + N)); // 128*128
    unsigned short* wf2 = wf1 + 128 * 128;                              // 128*128
    unsigned short* wf3 = wf2 + 128 * 128;                              // 128*64
    float* part = (float*)(wf3 + 128 * 64);      // NBLK128 * 256 floats (max)

    // ---- one-time prep: W -> fragment-ordered bf16 ----
    prep_wfrag<128><<<64, 256, 0, stream>>>(W1, wf1);
    prep_wfrag<128><<<64, 256, 0, stream>>>(W2, wf2);
    prep_wfrag<64><<<32, 256, 0, stream>>>(W3, wf3);

    // ---- CSR build (once; reused by all 3 layers) ----
    fill_i32<<<128, 256, 0, stream>>>(count, 0, N);
    dst_count<<<2048, 256, 0, stream>>>(ei, E, N, count, ord);
    block_sum<<<NB, 256, 0, stream>>>(count, bsum, N);
    scan_bsum<<<1, 256, 0, stream>>>(bsum, NB, rowptr, N, E + N);
    scan_final<<<NB, 256, 0, stream>>>(count, bsum, rowptr, N);
    csr_scatter<<<2048, 256, 0, stream>>>(ei, E, N, rowptr, ord, srcs);

    // L1: x -> aggA (no input BN); stats -> cs0
    run_layer<4, 32, false>(x, N, rowptr, srcs, wf1, as1, ad1,
                            nullptr, nullptr, nullptr,
                            hbuf, als, ald, part, cs0, aggA, stream);
    // L2: aggA (+BN1+ELU fused) -> aggB; stats -> cs1
    run_layer<4, 32, true>(aggA, N, rowptr, srcs, wf2, as2, ad2,
                           cs0, g1, be1,
                           hbuf, als, ald, part, cs1, aggB, stream);
    // L3: aggB (+BN2+ELU fused) -> aggA (D=64); stats -> cs2
    run_layer<1, 64, true>(aggB, N, rowptr, srcs, wf3, as3, ad3,
                           cs1, g2, be2,
                           hbuf, als, ald, part, cs2, aggA, stream);
    // final BN3 + ELU -> out
    bn_apply_v2<64><<<2048, 256, 0, stream>>>(aggA, cs2, g3, be3, (float*)d_out, N, 1.f / (float)N);
}

// Round 14
// 227.168 us; speedup vs baseline: 7.4287x; 1.0898x over previous
//
#include <hip/hip_runtime.h>
#include <hip/hip_bf16.h>
#include <math.h>

#define NEG_SLOPE 0.2f
#define BN_EPS 1e-5f

using short8_t = __attribute__((ext_vector_type(8))) short;
using f32x4    = __attribute__((ext_vector_type(4))) float;

__device__ __forceinline__ unsigned short f2bf(float f) {
    unsigned int u = __float_as_uint(f);
    u += 0x7FFF + ((u >> 16) & 1);          // round-to-nearest-even
    return (unsigned short)(u >> 16);
}
__device__ __forceinline__ float bf2f(unsigned short h) {
    return __uint_as_float(((unsigned int)h) << 16);
}

// ---------- consolidated setup: 3x W-frag pack + count zeroing ----------

__device__ __forceinline__ void wfrag_one(const float* __restrict__ W,
                                          unsigned short* __restrict__ Wf,
                                          int idx, int D)
{
    int CS = D / 32;
    int i    = idx & 7;
    int lane = (idx >> 3) & 63;
    int f    = idx >> 9;
    int ks   = f & 3;
    int cs   = (f >> 2) % CS;
    int wc   = (f >> 2) / CS;
    int k = ks * 32 + ((lane >> 4) << 3) + i;
    int d = wc * (D / 2) + cs * 16 + (lane & 15);
    Wf[idx] = f2bf(W[k * D + d]);
}

__global__ void setup_all(const float* __restrict__ W1, const float* __restrict__ W2,
                          const float* __restrict__ W3,
                          unsigned short* __restrict__ wf1, unsigned short* __restrict__ wf2,
                          unsigned short* __restrict__ wf3,
                          int* __restrict__ count, int N)
{
    int total = 16384 + 16384 + 8192 + N;
    int st = gridDim.x * blockDim.x;
    for (int idx = blockIdx.x * blockDim.x + threadIdx.x; idx < total; idx += st) {
        if (idx < 16384)       wfrag_one(W1, wf1, idx, 128);
        else if (idx < 32768)  wfrag_one(W2, wf2, idx - 16384, 128);
        else if (idx < 40960)  wfrag_one(W3, wf3, idx - 32768, 64);
        else                   count[idx - 40960] = 0;
    }
}

// ---------- CSR build (graph static across layers; built once per call) ----------

__global__ void dst_count(const int* __restrict__ ei, int E, int N,
                          int* __restrict__ count, int* __restrict__ ord)
{
    long long total = (long long)E + N;
    long long st = (long long)gridDim.x * blockDim.x;
    for (long long e = (long long)blockIdx.x * blockDim.x + threadIdx.x; e < total; e += st) {
        int dt = (e < E) ? ei[E + e] : (int)(e - E);
        ord[e] = atomicAdd(&count[dt], 1);
    }
}

__global__ void block_sum(const int* __restrict__ count, int* __restrict__ bsum, int N)
{
    __shared__ int sh[256];
    int b = blockIdx.x, t = threadIdx.x;
    int base = b * 1024;
    int s = 0;
    for (int i = t; i < 1024; i += 256) {
        int j = base + i;
        if (j < N) s += count[j];
    }
    sh[t] = s;
    __syncthreads();
    for (int off = 128; off > 0; off >>= 1) {
        if (t < off) sh[t] += sh[t + off];
        __syncthreads();
    }
    if (t == 0) bsum[b] = sh[0];
}

__global__ void scan_bsum(int* __restrict__ bsum, int nb, int* __restrict__ rowptr, int N, int total)
{
    __shared__ int sh[256];
    int t = threadIdx.x;
    sh[t] = (t < nb) ? bsum[t] : 0;
    __syncthreads();
    for (int off = 1; off < 256; off <<= 1) {
        int u = (t >= off) ? sh[t - off] : 0;
        __syncthreads();
        sh[t] += u;
        __syncthreads();
    }
    if (t < nb) bsum[t] = (t == 0) ? 0 : sh[t - 1];
    if (t == 0) rowptr[N] = total;
}

__global__ void scan_final(const int* __restrict__ count, const int* __restrict__ boff,
                           int* __restrict__ rowptr, int N)
{
    __shared__ int sh[256];
    int b = blockIdx.x, t = threadIdx.x;
    int base = b * 1024 + t * 4;
    int c[4];
    int s = 0;
    #pragma unroll
    for (int i = 0; i < 4; ++i) {
        int j = base + i;
        c[i] = (j < N) ? count[j] : 0;
        s += c[i];
    }
    sh[t] = s;
    __syncthreads();
    for (int off = 1; off < 256; off <<= 1) {
        int u = (t >= off) ? sh[t - off] : 0;
        __syncthreads();
        sh[t] += u;
        __syncthreads();
    }
    int run = boff[b] + ((t == 0) ? 0 : sh[t - 1]);
    #pragma unroll
    for (int i = 0; i < 4; ++i) {
        int j = base + i;
        if (j < N) rowptr[j] = run;
        run += c[i];
    }
}

__global__ void csr_scatter(const int* __restrict__ ei, int E, int N,
                            const int* __restrict__ rowptr, const int* __restrict__ ord,
                            int* __restrict__ srcs)
{
    long long total = (long long)E + N;
    long long st = (long long)gridDim.x * blockDim.x;
    for (long long e = (long long)blockIdx.x * blockDim.x + threadIdx.x; e < total; e += st) {
        int s, dt;
        if (e < E) { s = ei[e]; dt = ei[E + e]; }
        else       { s = dt = (int)(e - E); }
        srcs[rowptr[dt] + ord[e]] = s;
    }
}

// ---------- MFMA GEMM with fused BN-in / bf16-out / als-ald epilogue ----------

// 4 waves (2x2), 32 rows x D cols per block, K=128. B fragments in registers
// from L2-resident Wf. als/ald (attention projections) computed from the f32
// accumulators via 16-lane shfl reduce (R14: removes calc_al + hbuf re-read).
template<int D, int H, bool BN>
__global__ __launch_bounds__(256, 4) void gemm_mfma(
        const float* __restrict__ x, const unsigned short* __restrict__ Wf,
        const float* __restrict__ colstats, const float* __restrict__ g,
        const float* __restrict__ be,
        const float* __restrict__ a_s, const float* __restrict__ a_d,
        unsigned short* __restrict__ hbuf,
        float* __restrict__ als, float* __restrict__ ald,
        int N, float invN)
{
    constexpr int CS = D / 32;
    __shared__ unsigned short xs[32 * 136];
    __shared__ float affA[128], affB[128];
    __shared__ float red2[4][4][4][2];   // D=64 cross-wave als combine
    int tid = threadIdx.x, lane = tid & 63, w = tid >> 6;
    int wr = w >> 1, wc = w & 1;
    int n0 = blockIdx.x * 32;

    short8_t bfr[CS][4];
    #pragma unroll
    for (int cs = 0; cs < CS; ++cs)
        #pragma unroll
        for (int ks = 0; ks < 4; ++ks)
            bfr[cs][ks] = *(const short8_t*)(Wf + (((wc * CS + cs) * 4 + ks) << 9) + (lane << 3));

    if (BN) {
        if (tid < 128) {
            float cs_ = colstats[tid], cq = colstats[tid + 128];
            float mu = cs_ * invN;
            float var = cq * invN - mu * mu;
            float s = rsqrtf(var + BN_EPS) * g[tid];
            affA[tid] = s;
            affB[tid] = be[tid] - mu * s;
        }
        __syncthreads();
    }

    for (int jj = tid; jj < 32 * 32; jj += 256) {
        int r = jj >> 5, q = jj & 31;
        float4 v = make_float4(0.f, 0.f, 0.f, 0.f);
        if (n0 + r < N) v = *(const float4*)(x + (long long)(n0 + r) * 128 + q * 4);
        if (BN) {
            int c = q * 4;
            v.x = affA[c]     * v.x + affB[c];
            v.y = affA[c + 1] * v.y + affB[c + 1];
            v.z = affA[c + 2] * v.z + affB[c + 2];
            v.w = affA[c + 3] * v.w + affB[c + 3];
            v.x = (v.x > 0.f) ? v.x : expm1f(v.x);
            v.y = (v.y > 0.f) ? v.y : expm1f(v.y);
            v.z = (v.z > 0.f) ? v.z : expm1f(v.z);
            v.w = (v.w > 0.f) ? v.w : expm1f(v.w);
        }
        ushort4 o;
        o.x = f2bf(v.x); o.y = f2bf(v.y); o.z = f2bf(v.z); o.w = f2bf(v.w);
        *(ushort4*)(xs + r * 136 + q * 4) = o;
    }
    __syncthreads();

    f32x4 acc[CS];
    #pragma unroll
    for (int cs = 0; cs < CS; ++cs) acc[cs] = (f32x4){0.f, 0.f, 0.f, 0.f};

    #pragma unroll
    for (int ks = 0; ks < 4; ++ks) {
        short8_t a = *(const short8_t*)(xs + (wr * 16 + (lane & 15)) * 136
                                           + ks * 32 + ((lane >> 4) << 3));
        #pragma unroll
        for (int cs = 0; cs < CS; ++cs)
            acc[cs] = __builtin_amdgcn_mfma_f32_16x16x32_bf16(a, bfr[cs][ks], acc[cs], 0, 0, 0);
    }

    int mrow = wr * 16 + ((lane >> 4) << 2);
    int dcol = wc * (D / 2) + (lane & 15);
    #pragma unroll
    for (int cs = 0; cs < CS; ++cs)
        #pragma unroll
        for (int r = 0; r < 4; ++r) {
            int n = n0 + mrow + r;
            if (n < N) hbuf[(long long)n * D + dcol + cs * 16] = f2bf(acc[cs][r]);
        }

    // ---- fused attention projections ----
    int l15 = lane & 15;
    if (H == 4) {
        // wave covers 2 full heads (C=32): in-wave reduce only
        float ps[2][4], pd[2][4];
        #pragma unroll
        for (int ch = 0; ch < 2; ++ch) {
            int hh = wc * 2 + ch;
            #pragma unroll
            for (int r = 0; r < 4; ++r) { ps[ch][r] = 0.f; pd[ch][r] = 0.f; }
            #pragma unroll
            for (int k2 = 0; k2 < 2; ++k2) {
                int cs = ch * 2 + k2;
                int cih = k2 * 16 + l15;
                float as_v = a_s[hh * 32 + cih];
                float ad_v = a_d[hh * 32 + cih];
                #pragma unroll
                for (int r = 0; r < 4; ++r) {
                    ps[ch][r] += acc[cs][r] * as_v;
                    pd[ch][r] += acc[cs][r] * ad_v;
                }
            }
        }
        #pragma unroll
        for (int off = 1; off < 16; off <<= 1)
            #pragma unroll
            for (int ch = 0; ch < 2; ++ch)
                #pragma unroll
                for (int r = 0; r < 4; ++r) {
                    ps[ch][r] += __shfl_xor(ps[ch][r], off);
                    pd[ch][r] += __shfl_xor(pd[ch][r], off);
                }
        if (l15 == 0) {
            #pragma unroll
            for (int r = 0; r < 4; ++r) {
                int n = n0 + mrow + r;
                if (n < N) {
                    #pragma unroll
                    for (int ch = 0; ch < 2; ++ch) {
                        als[(long long)n * 4 + wc * 2 + ch] = ps[ch][r];
                        ald[(long long)n * 4 + wc * 2 + ch] = pd[ch][r];
                    }
                }
            }
        }
    } else {
        // H==1, D=64: head spans both col-waves -> LDS combine
        float ps[4], pd[4];
        #pragma unroll
        for (int r = 0; r < 4; ++r) { ps[r] = 0.f; pd[r] = 0.f; }
        #pragma unroll
        for (int cs = 0; cs < CS; ++cs) {
            int c = wc * 32 + cs * 16 + l15;
            float as_v = a_s[c], ad_v = a_d[c];
            #pragma unroll
            for (int r = 0; r < 4; ++r) {
                ps[r] += acc[cs][r] * as_v;
                pd[r] += acc[cs][r] * ad_v;
            }
        }
        #pragma unroll
        for (int off = 1; off < 16; off <<= 1)
            #pragma unroll
            for (int r = 0; r < 4; ++r) {
                ps[r] += __shfl_xor(ps[r], off);
                pd[r] += __shfl_xor(pd[r], off);
            }
        int q = lane >> 4;
        if (l15 == 0) {
            #pragma unroll
            for (int r = 0; r < 4; ++r) {
                red2[w][q][r][0] = ps[r];
                red2[w][q][r][1] = pd[r];
            }
        }
        __syncthreads();
        if (tid < 64) {
            int wr2 = tid >> 5, row = (tid >> 1) & 15, sd = tid & 1;
            int qq = row >> 2, rr = row & 3;
            float v = red2[wr2 * 2][qq][rr][sd] + red2[wr2 * 2 + 1][qq][rr][sd];
            int n = n0 + wr2 * 16 + row;
            if (n < N) { if (sd) ald[n] = v; else als[n] = v; }
        }
    }
}

// aggregate v5b: fused BN stats, contention-free partials (R13)
template<int H, int C>
__global__ __launch_bounds__(256) void gat_aggregate_v5(
        const int* __restrict__ rowptr, const int* __restrict__ srcs,
        const float* __restrict__ als, const float* __restrict__ ald,
        const unsigned short* __restrict__ hbuf, float* __restrict__ agg,
        float* __restrict__ part, int N)
{
    constexpr int D = H * C;
    constexpr int TPN = D / 8;
    constexpr int NPB = 256 / TPN;
    __shared__ float red[4][TPN * 16];
    int tid = threadIdx.x;
    int g = tid / TPN, l = tid % TPN;
    int n = blockIdx.x * NPB + g;
    bool active = (n < N);
    int c0 = l * 8;
    int hh = c0 / C;
    float aldv = active ? ald[(long long)n * H + hh] : 0.f;
    int beg = 0, end = 0;
    if (active) { beg = rowptr[n]; end = rowptr[n + 1]; }

    float wsum = 0.f;
    float acc[8];
    #pragma unroll
    for (int i = 0; i < 8; ++i) acc[i] = 0.f;

    int e = beg;
    for (; e + 4 <= end; e += 4) {
        int s0 = srcs[e], s1 = srcs[e + 1], s2 = srcs[e + 2], s3 = srcs[e + 3];
        float v0 = als[(long long)s0 * H + hh] + aldv;
        float v1 = als[(long long)s1 * H + hh] + aldv;
        float v2 = als[(long long)s2 * H + hh] + aldv;
        float v3 = als[(long long)s3 * H + hh] + aldv;
        v0 = (v0 >= 0.f) ? v0 : NEG_SLOPE * v0;
        v1 = (v1 >= 0.f) ? v1 : NEG_SLOPE * v1;
        v2 = (v2 >= 0.f) ? v2 : NEG_SLOPE * v2;
        v3 = (v3 >= 0.f) ? v3 : NEG_SLOPE * v3;
        float w0 = __expf(v0), w1 = __expf(v1), w2 = __expf(v2), w3 = __expf(v3);
        float4 q0 = *(const float4*)(hbuf + (long long)s0 * D + c0);
        float4 q1 = *(const float4*)(hbuf + (long long)s1 * D + c0);
        float4 q2 = *(const float4*)(hbuf + (long long)s2 * D + c0);
        float4 q3 = *(const float4*)(hbuf + (long long)s3 * D + c0);
        wsum += w0 + w1 + w2 + w3;
        const float* qf0 = (const float*)&q0;
        const float* qf1 = (const float*)&q1;
        const float* qf2 = (const float*)&q2;
        const float* qf3 = (const float*)&q3;
        #pragma unroll
        for (int i = 0; i < 4; ++i) {
            unsigned int u0 = __float_as_uint(qf0[i]);
            unsigned int u1 = __float_as_uint(qf1[i]);
            unsigned int u2 = __float_as_uint(qf2[i]);
            unsigned int u3 = __float_as_uint(qf3[i]);
            acc[2*i]   += w0 * __uint_as_float(u0 << 16)
                        + w1 * __uint_as_float(u1 << 16)
                        + w2 * __uint_as_float(u2 << 16)
                        + w3 * __uint_as_float(u3 << 16);
            acc[2*i+1] += w0 * __uint_as_float(u0 & 0xFFFF0000u)
                        + w1 * __uint_as_float(u1 & 0xFFFF0000u)
                        + w2 * __uint_as_float(u2 & 0xFFFF0000u)
                        + w3 * __uint_as_float(u3 & 0xFFFF0000u);
        }
    }
    for (; e < end; ++e) {
        int s = srcs[e];
        float v = als[(long long)s * H + hh] + aldv;
        v = (v >= 0.f) ? v : NEG_SLOPE * v;
        float w = __expf(v);
        float4 q = *(const float4*)(hbuf + (long long)s * D + c0);
        const float* qf = (const float*)&q;
        wsum += w;
        #pragma unroll
        for (int i = 0; i < 4; ++i) {
            unsigned int u = __float_as_uint(qf[i]);
            acc[2*i]   += w * __uint_as_float(u << 16);
            acc[2*i+1] += w * __uint_as_float(u & 0xFFFF0000u);
        }
    }
    float inv = active ? 1.f / (wsum + 1e-16f) : 0.f;
    float sv[16];
    #pragma unroll
    for (int i = 0; i < 8; ++i) {
        float o = acc[i] * inv;
        sv[i] = o;
        sv[8 + i] = o * o;
        acc[i] = o;
    }
    if (active) {
        *(float4*)(agg + (long long)n * D + c0)     = make_float4(acc[0], acc[1], acc[2], acc[3]);
        *(float4*)(agg + (long long)n * D + c0 + 4) = make_float4(acc[4], acc[5], acc[6], acc[7]);
    }

    #pragma unroll
    for (int off = TPN; off < 64; off <<= 1)
        #pragma unroll
        for (int j = 0; j < 16; ++j)
            sv[j] += __shfl_xor(sv[j], off);

    int w4 = tid >> 6, lane = tid & 63;
    if (lane < TPN) {
        #pragma unroll
        for (int j = 0; j < 16; ++j) red[w4][lane * 16 + j] = sv[j];
    }
    __syncthreads();
    if (w4 == 0 && lane < TPN) {
        #pragma unroll
        for (int ww = 1; ww < 4; ++ww)
            #pragma unroll
            for (int j = 0; j < 16; ++j) sv[j] += red[ww][lane * 16 + j];
        float* p = part + (long long)blockIdx.x * (2 * D) + lane * 16;
        *(float4*)(p)      = make_float4(sv[0],  sv[1],  sv[2],  sv[3]);
        *(float4*)(p + 4)  = make_float4(sv[4],  sv[5],  sv[6],  sv[7]);
        *(float4*)(p + 8)  = make_float4(sv[8],  sv[9],  sv[10], sv[11]);
        *(float4*)(p + 12) = make_float4(sv[12], sv[13], sv[14], sv[15]);
    }
}

// reduce per-block partials -> colsum (no contended atomics)
template<int D>
__global__ __launch_bounds__(256) void reduce_stats(
        const float* __restrict__ part, int nblk, float* __restrict__ colsum)
{
    __shared__ float sh[256];
    int f = blockIdx.x;
    int t = threadIdx.x;
    int col = (f < D) ? f : (f - D);
    int off = (col / 8) * 16 + (col % 8) + ((f < D) ? 0 : 8);
    float s = 0.f;
    for (int i = t; i < nblk; i += 256)
        s += part[(long long)i * (2 * D) + off];
    sh[t] = s;
    __syncthreads();
    for (int o = 128; o > 0; o >>= 1) {
        if (t < o) sh[t] += sh[t + o];
        __syncthreads();
    }
    if (t == 0) colsum[(f < D) ? f : (128 + f - D)] = sh[0];
}

// bn_apply_v2 (final output only)
template<int D>
__global__ __launch_bounds__(256) void bn_apply_v2(
        const float* __restrict__ agg, const float* __restrict__ colsum,
        const float* __restrict__ g, const float* __restrict__ be,
        float* __restrict__ out, int N, float invN)
{
    constexpr int TPR = D / 4;
    constexpr int RPB = 256 / TPR;
    __shared__ float affA[D], affB[D];
    int tid = threadIdx.x;
    if (tid < D) {
        float mu = colsum[tid] * invN;
        float var = colsum[128 + tid] * invN - mu * mu;
        float s = rsqrtf(var + BN_EPS) * g[tid];
        affA[tid] = s;
        affB[tid] = be[tid] - mu * s;
    }
    __syncthreads();
    int rg = tid / TPR, cl = tid % TPR;
    int c = cl * 4;
    float a0 = affA[c], a1 = affA[c+1], a2 = affA[c+2], a3 = affA[c+3];
    float b0 = affB[c], b1 = affB[c+1], b2 = affB[c+2], b3 = affB[c+3];
    for (int r = blockIdx.x * RPB + rg; r < N; r += gridDim.x * RPB) {
        float4 v = *(const float4*)(agg + (long long)r * D + c);
        v.x = a0 * v.x + b0; v.y = a1 * v.y + b1;
        v.z = a2 * v.z + b2; v.w = a3 * v.w + b3;
        v.x = (v.x > 0.f) ? v.x : expm1f(v.x);
        v.y = (v.y > 0.f) ? v.y : expm1f(v.y);
        v.z = (v.z > 0.f) ? v.z : expm1f(v.z);
        v.w = (v.w > 0.f) ? v.w : expm1f(v.w);
        *(float4*)(out + (long long)r * D + c) = v;
    }
}

template<int H, int C, bool BN>
static void run_layer(const float* xin, int N,
                      const int* rowptr, const int* srcs,
                      const unsigned short* Wf, const float* a_s, const float* a_d,
                      const float* prev_stats, const float* prev_g, const float* prev_be,
                      unsigned short* hbuf, float* als, float* ald,
                      float* part, float* stats_out, float* agg,
                      hipStream_t stream)
{
    constexpr int D = H * C;
    constexpr int NPB = 256 / (D / 8);
    int nblk = (N + NPB - 1) / NPB;
    float invN = 1.f / (float)N;
    gemm_mfma<D, H, BN><<<(N + 31) / 32, 256, 0, stream>>>(
        xin, Wf, prev_stats, prev_g, prev_be, a_s, a_d, hbuf, als, ald, N, invN);
    gat_aggregate_v5<H, C><<<nblk, 256, 0, stream>>>(
        rowptr, srcs, als, ald, hbuf, agg, part, N);
    reduce_stats<D><<<2 * D, 256, 0, stream>>>(part, nblk, stats_out);
}

extern "C" void kernel_launch(void* const* d_in, const int* in_sizes, int n_in,
                              void* d_out, int out_size, void* d_ws, size_t ws_size,
                              hipStream_t stream)
{
    const float* x   = (const float*)d_in[0];
    const int*   ei  = (const int*)d_in[1];
    const float* W1  = (const float*)d_in[2];
    const float* as1 = (const float*)d_in[3];
    const float* ad1 = (const float*)d_in[4];
    const float* g1  = (const float*)d_in[6];
    const float* be1 = (const float*)d_in[7];
    const float* W2  = (const float*)d_in[8];
    const float* as2 = (const float*)d_in[9];
    const float* ad2 = (const float*)d_in[10];
    const float* g2  = (const float*)d_in[12];
    const float* be2 = (const float*)d_in[13];
    const float* W3  = (const float*)d_in[14];
    const float* as3 = (const float*)d_in[15];
    const float* ad3 = (const float*)d_in[16];
    const float* g3  = (const float*)d_in[18];
    const float* be3 = (const float*)d_in[19];

    const int N = in_sizes[0] / 128;
    const int E = in_sizes[1] / 2;
    const int NB = (N + 1023) / 1024;

    float* ws   = (float*)d_ws;
    float* aggA = ws;                            // N*128
    float* aggB = aggA + (long long)N * 128;     // N*128
    float* als  = aggB + (long long)N * 128;     // N*4
    float* ald  = als  + (long long)N * 4;       // N*4
    float* cs0  = ald  + (long long)N * 4;       // 256
    float* cs1  = cs0 + 256;                     // 256
    float* cs2  = cs1 + 256;                     // 256
    unsigned short* hbuf = (unsigned short*)(cs2 + 256);        // N*128 bf16
    int*   rowptr = (int*)(hbuf + (long long)N * 128);          // N+1
    int*   count  = rowptr + (N + 1);            // N
    int*   bsum   = count + N;                   // <=256
    int*   ord    = bsum + 256;                  // E+N
    int*   srcs   = ord + ((long long)E + N);    // E+N
    unsigned short* wf1 = (unsigned short*)(srcs + ((long long)E + N)); // 128*128
    unsigned short* wf2 = wf1 + 128 * 128;                              // 128*128
    unsigned short* wf3 = wf2 + 128 * 128;                              // 128*64
    float* part = (float*)(wf3 + 128 * 64);      // ceil(N/16)*256 floats (max)

    // ---- setup (W-frag packs + count zeroing, one launch) ----
    setup_all<<<356, 256, 0, stream>>>(W1, W2, W3, wf1, wf2, wf3, count, N);

    // ---- CSR build ----
    dst_count<<<2048, 256, 0, stream>>>(ei, E, N, count, ord);
    block_sum<<<NB, 256, 0, stream>>>(count, bsum, N);
    scan_bsum<<<1, 256, 0, stream>>>(bsum, NB, rowptr, N, E + N);
    scan_final<<<NB, 256, 0, stream>>>(count, bsum, rowptr, N);
    csr_scatter<<<2048, 256, 0, stream>>>(ei, E, N, rowptr, ord, srcs);

    // L1: x -> aggA; stats -> cs0
    run_layer<4, 32, false>(x, N, rowptr, srcs, wf1, as1, ad1,
                            nullptr, nullptr, nullptr,
                            hbuf, als, ald, part, cs0, aggA, stream);
    // L2: aggA (+BN1+ELU fused) -> aggB; stats -> cs1
    run_layer<4, 32, true>(aggA, N, rowptr, srcs, wf2, as2, ad2,
                           cs0, g1, be1,
                           hbuf, als, ald, part, cs1, aggB, stream);
    // L3: aggB (+BN2+ELU fused) -> aggA (D=64); stats -> cs2
    run_layer<1, 64, true>(aggB, N, rowptr, srcs, wf3, as3, ad3,
                           cs1, g2, be2,
                           hbuf, als, ald, part, cs2, aggA, stream);
    // final BN3 + ELU -> out
    bn_apply_v2<64><<<2048, 256, 0, stream>>>(aggA, cs2, g3, be3, (float*)d_out, N, 1.f / (float)N);
}